// Round 7
// baseline (1030.982 us; speedup 1.0000x reference)
//
#include <hip/hip_runtime.h>
#include <hip/hip_bf16.h>
#include <math.h>

typedef __hip_bfloat16 bf16;
typedef short short8 __attribute__((ext_vector_type(8)));
typedef float f32x4 __attribute__((ext_vector_type(4)));

__device__ __forceinline__ float b2f(const bf16 v) { return __bfloat162float(v); }
__device__ __forceinline__ bf16 f2b(const float v) { return __float2bfloat16(v); }

__device__ __forceinline__ float ldsel(const void* p, size_t i, int f32) {
  return f32 ? ((const float*)p)[i] : b2f(((const bf16*)p)[i]);
}
__device__ __forceinline__ void stsel(void* p, size_t i, float v, int f32) {
  if (f32) ((float*)p)[i] = v; else ((bf16*)p)[i] = f2b(v);
}

#define NN 3712          // nodes
#define NE 37120         // edges (without self loops)
#define NG 32            // graphs
#define NREG 116         // nodes per graph
#define MAXDEG 32        // bucket capacity (in-degree ~ Poisson(10); P(>32) ~ 1e-9)

// ---------------- dtype detector ----------------
__global__ __launch_bounds__(256) void k_detect(const void* nf, const void* w0, int* flags) {
  __shared__ int bad[2];
  if (threadIdx.x < 2) bad[threadIdx.x] = 0;
  __syncthreads();
  const bf16* a = (const bf16*)nf;
  const bf16* b = (const bf16*)w0;
  int l0 = 0, l1 = 0;
  for (int i = threadIdx.x; i < 4096; i += 256) {
    float x = b2f(a[i]); if (!(fabsf(x) < 1e4f)) l0++;
    float y = b2f(b[i]); if (!(fabsf(y) < 1e4f)) l1++;
  }
  if (l0) atomicAdd(&bad[0], l0);
  if (l1) atomicAdd(&bad[1], l1);
  __syncthreads();
  if (threadIdx.x == 0) { flags[0] = bad[0] > 0; flags[1] = bad[1] > 0; }
}

// ---------------- utility kernels ----------------
__global__ __launch_bounds__(256) void k_zero(int* __restrict__ p, int n) {
  int i = blockIdx.x * 256 + threadIdx.x;
  if (i < n) p[i] = 0;
}

__global__ __launch_bounds__(256) void k_scatter(const int* __restrict__ src, const int* __restrict__ dst,
                                                 int* __restrict__ cnt, int* __restrict__ bucket, int E) {
  int e = blockIdx.x * 256 + threadIdx.x;
  if (e < E) {
    int d = dst[e], s = src[e];
    if ((unsigned)d < NN && (unsigned)s < NN) {
      int p = atomicAdd(&cnt[d], 1);
      if (p < MAXDEG) bucket[d * MAXDEG + p] = s;
    }
  }
}

__global__ __launch_bounds__(256) void k_tobf16(const void* __restrict__ in, bf16* __restrict__ out,
                                                int n, const int* __restrict__ flags, int fidx) {
  int f = flags[fidx];
  int i = blockIdx.x * 256 + threadIdx.x;
  if (i < n) out[i] = f2b(ldsel(in, i, f));
}

// transpose W[K][N] -> Wt[N][K], bf16 out. K,N multiples of 32.
__global__ __launch_bounds__(256) void k_transpose(const void* __restrict__ W, bf16* __restrict__ Wt,
                                                   int K, int N, const int* __restrict__ flags) {
  int f = flags[1];
  __shared__ float tile[32][33];
  int tx = threadIdx.x & 31, ty = threadIdx.x >> 5;
  int k0 = blockIdx.x * 32, n0 = blockIdx.y * 32;
#pragma unroll
  for (int i = 0; i < 4; ++i)
    tile[ty + i * 8][tx] = ldsel(W, (size_t)(k0 + ty + i * 8) * N + n0 + tx, f);
  __syncthreads();
#pragma unroll
  for (int i = 0; i < 4; ++i)
    Wt[(size_t)(n0 + ty + i * 8) * K + k0 + tx] = f2b(tile[tx][ty + i * 8]);
}

// fold attention vectors into extra wt rows: wt[N+j][k]   = sum_c W[k][jC+c]*a_s[j][c]
//                                            wt[N+8+j][k] = sum_c W[k][jC+c]*a_d[j][c]
__global__ __launch_bounds__(256) void k_prew(const void* __restrict__ W, const void* __restrict__ a_s,
                                              const void* __restrict__ a_d, bf16* __restrict__ wt,
                                              int K, int N, int C, const int* __restrict__ flags) {
  int wF = flags[1];
  int k = blockIdx.x * 256 + threadIdx.x;
  if (k >= K) return;
#pragma unroll
  for (int j = 0; j < 8; ++j) {
    float sS = 0.f, sD = 0.f;
    for (int c = 0; c < C; ++c) {
      float w = ldsel(W, (size_t)k * N + j * C + c, wF);
      sS = fmaf(w, ldsel(a_s, j * C + c, wF), sS);
      sD = fmaf(w, ldsel(a_d, j * C + c, wF), sD);
    }
    wt[(size_t)(N + j) * K + k] = f2b(sS);
    wt[(size_t)(N + 8 + j) * K + k] = f2b(sD);
  }
}

// ---------------- MFMA bf16 NT GEMM, TRANSPOSED store: Ct[n][m] = sum_k A[m][k] Bt[n][k] ----------------
template<int BM, int BN>
__global__ __launch_bounds__(256) void k_gemm_t(const bf16* __restrict__ A, const bf16* __restrict__ Bt,
                                                bf16* __restrict__ Ct, int M, int K) {
  __shared__ short As[BM * 40];
  __shared__ short Bs[BN * 40];
  constexpr int NA = BM / 64;    // uint4 chunks per thread
  constexpr int NB = BN / 64;
  constexpr int BMW = BM / 2, BNW = BN / 2;
  constexpr int MT = BMW / 16, NT = BNW / 16;
  int tid = threadIdx.x, wave = tid >> 6, lane = tid & 63;
  int wr = wave >> 1, wc = wave & 1;
  int quad = lane >> 4, ml = lane & 15;
  int m0 = blockIdx.y * BM, n0 = blockIdx.x * BN;
  f32x4 acc[MT][NT];
#pragma unroll
  for (int i = 0; i < MT; ++i)
#pragma unroll
    for (int j = 0; j < NT; ++j)
#pragma unroll
      for (int r = 0; r < 4; ++r) acc[i][j][r] = 0.f;

  uint4 pa[NA], pb[NB];
#pragma unroll
  for (int i = 0; i < NA; ++i) {
    int c = tid + i * 256;
    pa[i] = *(const uint4*)&A[(size_t)(m0 + (c >> 2)) * K + (c & 3) * 8];
  }
#pragma unroll
  for (int i = 0; i < NB; ++i) {
    int c = tid + i * 256;
    pb[i] = *(const uint4*)&Bt[(size_t)(n0 + (c >> 2)) * K + (c & 3) * 8];
  }

  int nk = K >> 5;
  for (int ks = 0; ks < nk; ++ks) {
#pragma unroll
    for (int i = 0; i < NA; ++i) {
      int c = tid + i * 256;
      *(uint4*)&As[(c >> 2) * 40 + (c & 3) * 8] = pa[i];
    }
#pragma unroll
    for (int i = 0; i < NB; ++i) {
      int c = tid + i * 256;
      *(uint4*)&Bs[(c >> 2) * 40 + (c & 3) * 8] = pb[i];
    }
    __syncthreads();
    if (ks + 1 < nk) {
      int k0 = (ks + 1) << 5;
#pragma unroll
      for (int i = 0; i < NA; ++i) {
        int c = tid + i * 256;
        pa[i] = *(const uint4*)&A[(size_t)(m0 + (c >> 2)) * K + k0 + (c & 3) * 8];
      }
#pragma unroll
      for (int i = 0; i < NB; ++i) {
        int c = tid + i * 256;
        pb[i] = *(const uint4*)&Bt[(size_t)(n0 + (c >> 2)) * K + k0 + (c & 3) * 8];
      }
    }
    short8 af[MT], bfr[NT];
#pragma unroll
    for (int mt = 0; mt < MT; ++mt)
      af[mt] = *(const short8*)&As[(wr * BMW + mt * 16 + ml) * 40 + quad * 8];
#pragma unroll
    for (int ct = 0; ct < NT; ++ct)
      bfr[ct] = *(const short8*)&Bs[(wc * BNW + ct * 16 + ml) * 40 + quad * 8];
#pragma unroll
    for (int mt = 0; mt < MT; ++mt)
#pragma unroll
      for (int ct = 0; ct < NT; ++ct)
        acc[mt][ct] = __builtin_amdgcn_mfma_f32_16x16x32_bf16(af[mt], bfr[ct], acc[mt][ct], 0, 0, 0);
    __syncthreads();
  }
  // transposed store: Ct[col][rows], 4 consecutive rows per lane -> uint2
#pragma unroll
  for (int mt = 0; mt < MT; ++mt)
#pragma unroll
    for (int ct = 0; ct < NT; ++ct) {
      int grow = m0 + wr * BMW + mt * 16 + quad * 4;
      int gcol = n0 + wc * BNW + ct * 16 + ml;
      bf16 ov[4];
#pragma unroll
      for (int r = 0; r < 4; ++r) ov[r] = f2b(acc[mt][ct][r]);
      *(uint2*)&Ct[(size_t)gcol * M + grow] = *(uint2*)ov;
    }
}

// ---------------- fused GAT attention+aggregation as P@H MFMA ----------------
// One block per (g,h). Ht is feat-major [N'+16][NN]; rows 8C+h / 8C+8+h hold al/ar.
// Builds dense softmax-adjacency P (unnormalized, bf16) in LDS, MFMAs P@H^T slices,
// scales rows by 1/den in epilogue, writes node-major output to Xo (row stride 8C).
template<int C>
__global__ __launch_bounds__(256) void k_gagg2(const bf16* __restrict__ Ht, bf16* __restrict__ Xo,
                                               const int* __restrict__ cnt, const int* __restrict__ bucket) {
  constexpr int D = 8 * C;
  constexpr int LDP = 136;              // shorts; 272 B rows: 16B-aligned ds_read_b128
  int g = blockIdx.x >> 3, h = blockIdx.x & 7;
  int t = threadIdx.x, lane = t & 63, wave = t >> 6;
  int quad = lane >> 4, ml = lane & 15;
  int gbase = g * NREG;
  __shared__ short sP[128 * LDP];
  __shared__ short sHT[128 * LDP];
  __shared__ unsigned short sBkt[NREG * MAXDEG];
  __shared__ float sAl[NREG], sAr[NREG], sInv[NREG];

  // phase A: zero P, load al/ar, load bucket slice
  for (int i = t; i < 128 * LDP / 2; i += 256) ((unsigned*)sP)[i] = 0u;
  if (t < NREG) {
    sAl[t] = b2f(Ht[(size_t)(D + h) * NN + gbase + t]);
    sAr[t] = b2f(Ht[(size_t)(D + 8 + h) * NN + gbase + t]);
  }
  for (int i = t; i < NREG * MAXDEG; i += 256) {
    int v = bucket[gbase * MAXDEG + i] - gbase;
    sBkt[i] = (unsigned short)(((unsigned)v < NREG) ? v : 0);
  }
  __syncthreads();

  // phase B: per-dst softmax -> unnormalized P row + 1/den
  if (t < NREG) {
    int d = t;
    int deg = cnt[gbase + d]; deg = deg > MAXDEG ? MAXDEG : deg;
    float ard = sAr[d];
    float lgs = sAl[d] + ard; lgs = lgs > 0.f ? lgs : 0.2f * lgs;   // self loop
    float m = lgs;
    for (int e = 0; e < deg; ++e) {
      float lg = sAl[sBkt[d * MAXDEG + e]] + ard; lg = lg > 0.f ? lg : 0.2f * lg;
      m = fmaxf(m, lg);
    }
    float den = expf(lgs - m);
    { bf16* p = (bf16*)&sP[d * LDP + d]; *p = f2b(b2f(*p) + expf(lgs - m)); }
    for (int e = 0; e < deg; ++e) {
      int s = sBkt[d * MAXDEG + e];
      float lg = sAl[s] + ard; lg = lg > 0.f ? lg : 0.2f * lg;
      float x = expf(lg - m); den += x;
      bf16* p = (bf16*)&sP[d * LDP + s]; *p = f2b(b2f(*p) + x);   // duplicates accumulate
    }
    sInv[d] = 1.f / den;
  }
  __syncthreads();

  // phase C: chunks of <=128 output cols; MFMA P[128x128] @ Hchunk^T
  constexpr int MT = (C >= 128) ? 4 : 2;
  constexpr int NCH = (C >= 128) ? C / 128 : 1;
  constexpr int CROWS = (C >= 128) ? 128 : 64;
  int m0w = (C >= 128) ? (wave >> 1) * 64 : wave * 32;
  int n0w = (C >= 128) ? (wave & 1) * 64 : 0;
  for (int ch = 0; ch < NCH; ++ch) {
    // load H^T slice: LDS row r = out-col c, cols = src node s (0..115), pad 116..127 zero
    for (int job = t; job < CROWS * 32; job += 256) {
      int r = job >> 5, sl = job & 31;
      if (sl < 29)
        *(uint2*)&sHT[r * LDP + sl * 4] = *(const uint2*)&Ht[(size_t)(h * C + ch * 128 + r) * NN + gbase + sl * 4];
      else
        *(uint2*)&sHT[r * LDP + sl * 4] = make_uint2(0u, 0u);
    }
    __syncthreads();
    f32x4 acc[MT][4];
#pragma unroll
    for (int mt = 0; mt < MT; ++mt)
#pragma unroll
      for (int ct = 0; ct < 4; ++ct)
#pragma unroll
        for (int r = 0; r < 4; ++r) acc[mt][ct][r] = 0.f;
#pragma unroll
    for (int k4 = 0; k4 < 4; ++k4) {
      short8 af[MT], bfr[4];
#pragma unroll
      for (int mt = 0; mt < MT; ++mt)
        af[mt] = *(const short8*)&sP[(m0w + mt * 16 + ml) * LDP + k4 * 32 + quad * 8];
#pragma unroll
      for (int ct = 0; ct < 4; ++ct)
        bfr[ct] = *(const short8*)&sHT[(n0w + ct * 16 + ml) * LDP + k4 * 32 + quad * 8];
#pragma unroll
      for (int mt = 0; mt < MT; ++mt)
#pragma unroll
        for (int ct = 0; ct < 4; ++ct)
          acc[mt][ct] = __builtin_amdgcn_mfma_f32_16x16x32_bf16(af[mt], bfr[ct], acc[mt][ct], 0, 0, 0);
    }
    // epilogue: scale by 1/den, store node-major
#pragma unroll
    for (int mt = 0; mt < MT; ++mt)
#pragma unroll
      for (int ct = 0; ct < 4; ++ct) {
        int row0 = m0w + mt * 16 + quad * 4;
#pragma unroll
        for (int r = 0; r < 4; ++r) {
          int row = row0 + r;
          if (row < NREG)
            Xo[(size_t)(gbase + row) * D + h * C + ch * 128 + n0w + ct * 16 + ml] =
                f2b(acc[mt][ct][r] * sInv[row]);
        }
      }
    __syncthreads();
  }
}

// ---------------- epilogue: bias + ELU + LayerNorm (head-mean for last layer) ----------------
template<int C, int CONCAT>
__global__ __launch_bounds__(256) void k_post(const bf16* __restrict__ Hb, const void* __restrict__ bias,
                                              const void* __restrict__ ls, const void* __restrict__ lb,
                                              bf16* __restrict__ Xout, const int* __restrict__ flags) {
  constexpr int D = 8 * C;
  constexpr int V = D / 256;
  int wF = flags[1];
  int d = blockIdx.x, t = threadIdx.x;
  int lane = t & 63, wave = t >> 6;
  __shared__ float vals[CONCAT ? 8 : 512];
  __shared__ float r1[4], r2[4];
  __shared__ float sMu, sRs;
  int base = t * V;
  bf16 hv[V];
  if constexpr (V == 8) *(uint4*)hv = *(const uint4*)&Hb[(size_t)d * D + base];
  else if constexpr (V == 4) *(uint2*)hv = *(const uint2*)&Hb[(size_t)d * D + base];
  else *(unsigned*)hv = *(const unsigned*)&Hb[(size_t)d * D + base];

  if constexpr (CONCAT) {
    float acc[V];
    float s1 = 0.f, s2 = 0.f;
#pragma unroll
    for (int i = 0; i < V; ++i) {
      float v = b2f(hv[i]) + ldsel(bias, base + i, wF);
      v = v > 0.f ? v : expf(v) - 1.f;        // ELU
      acc[i] = v; s1 += v; s2 += v * v;
    }
#pragma unroll
    for (int off = 32; off; off >>= 1) { s1 += __shfl_down(s1, off); s2 += __shfl_down(s2, off); }
    if (lane == 0) { r1[wave] = s1; r2[wave] = s2; }
    __syncthreads();
    if (t == 0) {
      float S1 = r1[0] + r1[1] + r1[2] + r1[3];
      float S2 = r2[0] + r2[1] + r2[2] + r2[3];
      float mu = S1 / D;
      sMu = mu; sRs = rsqrtf(S2 / D - mu * mu + 1e-5f);
    }
    __syncthreads();
    bf16 ov[V];
#pragma unroll
    for (int i = 0; i < V; ++i)
      ov[i] = f2b((acc[i] - sMu) * sRs * ldsel(ls, base + i, wF) + ldsel(lb, base + i, wF));
    if constexpr (V == 8) *(uint4*)&Xout[(size_t)d * D + base] = *(uint4*)ov;
    else *(uint2*)&Xout[(size_t)d * D + base] = *(uint2*)ov;
  } else {
#pragma unroll
    for (int i = 0; i < V; ++i) vals[base + i] = b2f(hv[i]);
    __syncthreads();
    if (t < 64) {   // mean over 8 heads -> 64 dims, ELU, LN over 64
      float v = 0.f;
#pragma unroll
      for (int hh = 0; hh < 8; ++hh) v += vals[hh * 64 + t];
      v = v * 0.125f + ldsel(bias, t, wF);
      v = v > 0.f ? v : expf(v) - 1.f;
      float s1 = v, s2 = v * v;
#pragma unroll
      for (int off = 32; off; off >>= 1) { s1 += __shfl_xor(s1, off); s2 += __shfl_xor(s2, off); }
      float mu = s1 * (1.f / 64.f);
      float var = s2 * (1.f / 64.f) - mu * mu;
      float rs = rsqrtf(var + 1e-5f);
      Xout[(size_t)d * 64 + t] = f2b((v - mu) * rs * ldsel(ls, t, wF) + ldsel(lb, t, wF));
    }
  }
}

// ---------------- projection (64->256) + LN + GELU(erf) + q ----------------
__global__ __launch_bounds__(256) void k_proj(const bf16* __restrict__ X3, const void* __restrict__ wp,
                                              const void* __restrict__ bp, const void* __restrict__ lsp,
                                              const void* __restrict__ lbp, const void* __restrict__ wq,
                                              const void* __restrict__ bq,
                                              float* __restrict__ q, void* __restrict__ dout,
                                              const int* __restrict__ flags) {
  int wF = flags[1], xF = flags[0];
  int n = blockIdx.x, t = threadIdx.x;
  int lane = t & 63, wave = t >> 6;
  __shared__ float xs[64];
  __shared__ float r1[4], r2[4];
  __shared__ float sMu, sRs;
  if (t < 64) xs[t] = b2f(X3[n * 64 + t]);
  __syncthreads();
  float y = ldsel(bp, t, wF);
#pragma unroll 8
  for (int k = 0; k < 64; ++k) y = fmaf(xs[k], ldsel(wp, k * 256 + t, wF), y);
  float s1 = y, s2 = y * y;
#pragma unroll
  for (int off = 32; off; off >>= 1) { s1 += __shfl_down(s1, off); s2 += __shfl_down(s2, off); }
  if (lane == 0) { r1[wave] = s1; r2[wave] = s2; }
  __syncthreads();
  if (t == 0) {
    float S1 = r1[0] + r1[1] + r1[2] + r1[3];
    float S2 = r2[0] + r2[1] + r2[2] + r2[3];
    float mu = S1 / 256.f;
    sMu = mu; sRs = rsqrtf(S2 / 256.f - mu * mu + 1e-5f);
  }
  __syncthreads();
  float v = (y - sMu) * sRs * ldsel(lsp, t, wF) + ldsel(lbp, t, wF);
  float g = 0.5f * v * (1.f + erff(v * 0.70710678118654752f));   // exact GELU
  stsel(dout, (size_t)NG * 256 + (size_t)n * 256 + t, g, xF);    // node_out
  float qv = g * ldsel(wq, t, wF);
#pragma unroll
  for (int off = 32; off; off >>= 1) qv += __shfl_down(qv, off);
  if (lane == 0) r1[wave] = qv;
  __syncthreads();
  if (t == 0) q[n] = r1[0] + r1[1] + r1[2] + r1[3] + ldsel(bq, 0, wF);
}

// ---------------- attention pooling per graph ----------------
__global__ __launch_bounds__(256) void k_pool(void* __restrict__ dout, const float* __restrict__ q,
                                              const int* __restrict__ flags) {
  int xF = flags[0];
  int b = blockIdx.x, t = threadIdx.x;
  __shared__ float es[NREG];
  __shared__ float sDen;
  if (t < NREG) es[t] = q[b * NREG + t];
  __syncthreads();
  if (t == 0) {
    float m = -1e30f;
    for (int i = 0; i < NREG; ++i) m = fmaxf(m, es[i]);
    float den = 0.f;
    for (int i = 0; i < NREG; ++i) { float e = expf(es[i] - m); es[i] = e; den += e; }
    sDen = den;
  }
  __syncthreads();
  float acc = 0.f;
  for (int i = 0; i < NREG; ++i)
    acc = fmaf(es[i], ldsel(dout, (size_t)NG * 256 + (size_t)(b * NREG + i) * 256 + t, xF), acc);
  stsel(dout, (size_t)b * 256 + t, acc / sDen, xF);
}

// ---------------- launcher ----------------
extern "C" void kernel_launch(void* const* d_in, const int* in_sizes, int n_in,
                              void* d_out, int out_size, void* d_ws, size_t ws_size,
                              hipStream_t stream) {
  const void* nf  = d_in[0];
  const int* src  = (const int*)d_in[1];
  const int* dst  = (const int*)d_in[2];
  const void *w0 = d_in[4],  *b0 = d_in[5],  *as0 = d_in[6], *ad0 = d_in[7],  *ls0 = d_in[8],  *lb0 = d_in[9];
  const void *w1 = d_in[10], *b1 = d_in[11], *as1 = d_in[12], *ad1 = d_in[13], *ls1 = d_in[14], *lb1 = d_in[15];
  const void *w2 = d_in[16], *b2 = d_in[17], *as2 = d_in[18], *ad2 = d_in[19], *ls2 = d_in[20], *lb2 = d_in[21];
  const void *wp = d_in[22], *bp = d_in[23], *lsp = d_in[24], *lbp = d_in[25], *wq = d_in[26], *bq = d_in[27];

  // workspace layout — TOTAL ~31.9 MB
  int* flags  = (int*)d_ws;                       // 4 ints
  int* cnt    = flags + 4;                        // NN
  int* bucket = cnt + NN;                         // NN*MAXDEG(32)
  float* q    = (float*)(bucket + NN * MAXDEG);   // NN f32
  bf16* X     = (bf16*)(q + NN);                  // NN*2048 bf16 (16B-aligned)
  bf16* Ht    = X + (size_t)NN * 2048;            // 2176*NN bf16 (feat-major)

  bf16* X0  = X;                                  // NN*256 input copy (dead after gemm0)
  bf16* wt0 = X + (1 << 20);                      // 2176 x 256  (in X region, dead after gemm0)
  bf16* wt1 = Ht + (size_t)4500 * 1024;           // 1152 x 2048 (above gemm1's 1152*NN output)
  bf16* wt2 = Ht + (size_t)4500 * 1024;           // 640 x 1024  (above gemm2's 640*NN output)
  bf16* X2  = X + (size_t)4 * 1024 * 1024;        // NN*64 final LN output (clear of NN*512 region)

  k_detect<<<1, 256, 0, stream>>>(nf, w0, flags);
  k_zero<<<(NN + 255) / 256, 256, 0, stream>>>(cnt, NN);
  k_scatter<<<(NE + 255) / 256, 256, 0, stream>>>(src, dst, cnt, bucket, NE);
  k_tobf16<<<(NN * 256 + 255) / 256, 256, 0, stream>>>(nf, X0, NN * 256, flags, 0);

  // layer 0: 256 -> 2048 (+16 alr rows, N'=2176)
  k_transpose<<<dim3(256 / 32, 2048 / 32), 256, 0, stream>>>(w0, wt0, 256, 2048, flags);
  k_prew<<<1, 256, 0, stream>>>(w0, as0, ad0, wt0, 256, 2048, 256, flags);
  k_gemm_t<128, 128><<<dim3(2176 / 128, NN / 128), 256, 0, stream>>>(X0, wt0, Ht, NN, 256);
  k_gagg2<256><<<NG * 8, 256, 0, stream>>>(Ht, X, cnt, bucket);
  k_post<256, 1><<<NN, 256, 0, stream>>>(X, b0, ls0, lb0, X, flags);

  // layer 1: 2048 -> 1024 (+16, N'=1152)
  k_transpose<<<dim3(2048 / 32, 1024 / 32), 256, 0, stream>>>(w1, wt1, 2048, 1024, flags);
  k_prew<<<2048 / 256, 256, 0, stream>>>(w1, as1, ad1, wt1, 2048, 1024, 128, flags);
  k_gemm_t<64, 128><<<dim3(1152 / 128, NN / 64), 256, 0, stream>>>(X, wt1, Ht, NN, 2048);
  k_gagg2<128><<<NG * 8, 256, 0, stream>>>(Ht, X, cnt, bucket);
  k_post<128, 1><<<NN, 256, 0, stream>>>(X, b1, ls1, lb1, X, flags);

  // layer 2: 1024 -> 512 (+16, N'=640)
  k_transpose<<<dim3(1024 / 32, 512 / 32), 256, 0, stream>>>(w2, wt2, 1024, 512, flags);
  k_prew<<<1024 / 256, 256, 0, stream>>>(w2, as2, ad2, wt2, 1024, 512, 64, flags);
  k_gemm_t<64, 128><<<dim3(640 / 128, NN / 64), 256, 0, stream>>>(X, wt2, Ht, NN, 1024);
  k_gagg2<64><<<NG * 8, 256, 0, stream>>>(Ht, X, cnt, bucket);
  k_post<64, 0><<<NN, 256, 0, stream>>>(X, b2, ls2, lb2, X2, flags);

  // projection + GELU + q, then pooling
  k_proj<<<NN, 256, 0, stream>>>(X2, wp, bp, lsp, lbp, wq, bq, q, d_out, flags);
  k_pool<<<NG, 256, 0, stream>>>(d_out, q, flags);
}

// Round 8
// 672.458 us; speedup vs baseline: 1.5332x; 1.5332x over previous
//
#include <hip/hip_runtime.h>
#include <hip/hip_bf16.h>
#include <math.h>

typedef __hip_bfloat16 bf16;
typedef short short8 __attribute__((ext_vector_type(8)));
typedef float f32x4 __attribute__((ext_vector_type(4)));

__device__ __forceinline__ float b2f(const bf16 v) { return __bfloat162float(v); }
__device__ __forceinline__ bf16 f2b(const float v) { return __float2bfloat16(v); }

__device__ __forceinline__ float ldsel(const void* p, size_t i, int f32) {
  return f32 ? ((const float*)p)[i] : b2f(((const bf16*)p)[i]);
}
__device__ __forceinline__ void stsel(void* p, size_t i, float v, int f32) {
  if (f32) ((float*)p)[i] = v; else ((bf16*)p)[i] = f2b(v);
}

#define NN 3712          // nodes
#define NE 37120         // edges (without self loops)
#define NG 32            // graphs
#define NREG 116         // nodes per graph
#define MAXDEG 32        // bucket capacity (in-degree ~ Poisson(10); P(>32) ~ 1e-9)

// ---------------- dtype detector ----------------
__global__ __launch_bounds__(256) void k_detect(const void* nf, const void* w0, int* flags) {
  __shared__ int bad[2];
  if (threadIdx.x < 2) bad[threadIdx.x] = 0;
  __syncthreads();
  const bf16* a = (const bf16*)nf;
  const bf16* b = (const bf16*)w0;
  int l0 = 0, l1 = 0;
  for (int i = threadIdx.x; i < 4096; i += 256) {
    float x = b2f(a[i]); if (!(fabsf(x) < 1e4f)) l0++;
    float y = b2f(b[i]); if (!(fabsf(y) < 1e4f)) l1++;
  }
  if (l0) atomicAdd(&bad[0], l0);
  if (l1) atomicAdd(&bad[1], l1);
  __syncthreads();
  if (threadIdx.x == 0) { flags[0] = bad[0] > 0; flags[1] = bad[1] > 0; }
}

// ---------------- utility kernels ----------------
__global__ __launch_bounds__(256) void k_zero(int* __restrict__ p, int n) {
  int i = blockIdx.x * 256 + threadIdx.x;
  if (i < n) p[i] = 0;
}

__global__ __launch_bounds__(256) void k_scatter(const int* __restrict__ src, const int* __restrict__ dst,
                                                 int* __restrict__ cnt, int* __restrict__ bucket, int E) {
  int e = blockIdx.x * 256 + threadIdx.x;
  if (e < E) {
    int d = dst[e], s = src[e];
    if ((unsigned)d < NN && (unsigned)s < NN) {
      int p = atomicAdd(&cnt[d], 1);
      if (p < MAXDEG) bucket[d * MAXDEG + p] = s;
    }
  }
}

__global__ __launch_bounds__(256) void k_tobf16(const void* __restrict__ in, bf16* __restrict__ out,
                                                int n, const int* __restrict__ flags, int fidx) {
  int f = flags[fidx];
  int i = blockIdx.x * 256 + threadIdx.x;
  if (i < n) out[i] = f2b(ldsel(in, i, f));
}

// transpose W[K][N] -> Wt[N][K], bf16 out. K,N multiples of 32.
__global__ __launch_bounds__(256) void k_transpose(const void* __restrict__ W, bf16* __restrict__ Wt,
                                                   int K, int N, const int* __restrict__ flags) {
  int f = flags[1];
  __shared__ float tile[32][33];
  int tx = threadIdx.x & 31, ty = threadIdx.x >> 5;
  int k0 = blockIdx.x * 32, n0 = blockIdx.y * 32;
#pragma unroll
  for (int i = 0; i < 4; ++i)
    tile[ty + i * 8][tx] = ldsel(W, (size_t)(k0 + ty + i * 8) * N + n0 + tx, f);
  __syncthreads();
#pragma unroll
  for (int i = 0; i < 4; ++i)
    Wt[(size_t)(n0 + ty + i * 8) * K + k0 + tx] = f2b(tile[tx][ty + i * 8]);
}

// fold attention vectors into extra wt rows, reading the ALREADY-TRANSPOSED wt:
//   wt[N+j][k]   = sum_c wt[j*C+c][k] * a_s[j][c]
//   wt[N+8+j][k] = sum_c wt[j*C+c][k] * a_d[j][c]
// k = blockIdx.x*256+tid -> coalesced row reads; a_* loads are wave-uniform (scalar).
__global__ __launch_bounds__(256) void k_prew2(const void* __restrict__ a_s, const void* __restrict__ a_d,
                                               bf16* __restrict__ wt, int K, int N, int C,
                                               const int* __restrict__ flags) {
  int wF = flags[1];
  int j = blockIdx.y;
  int k = blockIdx.x * 256 + threadIdx.x;
  float sS = 0.f, sD = 0.f;
  for (int c = 0; c < C; ++c) {
    float w = b2f(wt[(size_t)(j * C + c) * K + k]);
    sS = fmaf(w, ldsel(a_s, j * C + c, wF), sS);
    sD = fmaf(w, ldsel(a_d, j * C + c, wF), sD);
  }
  wt[(size_t)(N + j) * K + k] = f2b(sS);
  wt[(size_t)(N + 8 + j) * K + k] = f2b(sD);
}

// ---------------- MFMA bf16 NT GEMM, TRANSPOSED store: Ct[n][m] = sum_k A[m][k] Bt[n][k] ----------------
template<int BM, int BN>
__global__ __launch_bounds__(256) void k_gemm_t(const bf16* __restrict__ A, const bf16* __restrict__ Bt,
                                                bf16* __restrict__ Ct, int M, int K) {
  __shared__ short As[BM * 40];
  __shared__ short Bs[BN * 40];
  constexpr int NA = BM / 64;    // uint4 chunks per thread
  constexpr int NB = BN / 64;
  constexpr int BMW = BM / 2, BNW = BN / 2;
  constexpr int MT = BMW / 16, NT = BNW / 16;
  int tid = threadIdx.x, wave = tid >> 6, lane = tid & 63;
  int wr = wave >> 1, wc = wave & 1;
  int quad = lane >> 4, ml = lane & 15;
  int m0 = blockIdx.y * BM, n0 = blockIdx.x * BN;
  f32x4 acc[MT][NT];
#pragma unroll
  for (int i = 0; i < MT; ++i)
#pragma unroll
    for (int j = 0; j < NT; ++j)
#pragma unroll
      for (int r = 0; r < 4; ++r) acc[i][j][r] = 0.f;

  uint4 pa[NA], pb[NB];
#pragma unroll
  for (int i = 0; i < NA; ++i) {
    int c = tid + i * 256;
    pa[i] = *(const uint4*)&A[(size_t)(m0 + (c >> 2)) * K + (c & 3) * 8];
  }
#pragma unroll
  for (int i = 0; i < NB; ++i) {
    int c = tid + i * 256;
    pb[i] = *(const uint4*)&Bt[(size_t)(n0 + (c >> 2)) * K + (c & 3) * 8];
  }

  int nk = K >> 5;
  for (int ks = 0; ks < nk; ++ks) {
#pragma unroll
    for (int i = 0; i < NA; ++i) {
      int c = tid + i * 256;
      *(uint4*)&As[(c >> 2) * 40 + (c & 3) * 8] = pa[i];
    }
#pragma unroll
    for (int i = 0; i < NB; ++i) {
      int c = tid + i * 256;
      *(uint4*)&Bs[(c >> 2) * 40 + (c & 3) * 8] = pb[i];
    }
    __syncthreads();
    if (ks + 1 < nk) {
      int k0 = (ks + 1) << 5;
#pragma unroll
      for (int i = 0; i < NA; ++i) {
        int c = tid + i * 256;
        pa[i] = *(const uint4*)&A[(size_t)(m0 + (c >> 2)) * K + k0 + (c & 3) * 8];
      }
#pragma unroll
      for (int i = 0; i < NB; ++i) {
        int c = tid + i * 256;
        pb[i] = *(const uint4*)&Bt[(size_t)(n0 + (c >> 2)) * K + k0 + (c & 3) * 8];
      }
    }
    short8 af[MT], bfr[NT];
#pragma unroll
    for (int mt = 0; mt < MT; ++mt)
      af[mt] = *(const short8*)&As[(wr * BMW + mt * 16 + ml) * 40 + quad * 8];
#pragma unroll
    for (int ct = 0; ct < NT; ++ct)
      bfr[ct] = *(const short8*)&Bs[(wc * BNW + ct * 16 + ml) * 40 + quad * 8];
#pragma unroll
    for (int mt = 0; mt < MT; ++mt)
#pragma unroll
      for (int ct = 0; ct < NT; ++ct)
        acc[mt][ct] = __builtin_amdgcn_mfma_f32_16x16x32_bf16(af[mt], bfr[ct], acc[mt][ct], 0, 0, 0);
    __syncthreads();
  }
  // transposed store: Ct[col][rows], 4 consecutive rows per lane -> uint2
#pragma unroll
  for (int mt = 0; mt < MT; ++mt)
#pragma unroll
    for (int ct = 0; ct < NT; ++ct) {
      int grow = m0 + wr * BMW + mt * 16 + quad * 4;
      int gcol = n0 + wc * BNW + ct * 16 + ml;
      bf16 ov[4];
#pragma unroll
      for (int r = 0; r < 4; ++r) ov[r] = f2b(acc[mt][ct][r]);
      *(uint2*)&Ct[(size_t)gcol * M + grow] = *(uint2*)ov;
    }
}

// ---------------- fused GAT attention+aggregation as P@H MFMA ----------------
// One block per (g,h). Ht is feat-major [N'+16][NN]; rows 8C+h / 8C+8+h hold al/ar.
template<int C>
__global__ __launch_bounds__(256) void k_gagg2(const bf16* __restrict__ Ht, bf16* __restrict__ Xo,
                                               const int* __restrict__ cnt, const int* __restrict__ bucket) {
  constexpr int D = 8 * C;
  constexpr int LDP = 136;              // shorts; 272 B rows: 16B-aligned ds_read_b128
  int g = blockIdx.x >> 3, h = blockIdx.x & 7;
  int t = threadIdx.x, lane = t & 63, wave = t >> 6;
  int quad = lane >> 4, ml = lane & 15;
  int gbase = g * NREG;
  __shared__ short sP[128 * LDP];
  __shared__ short sHT[128 * LDP];
  __shared__ unsigned short sBkt[NREG * MAXDEG];
  __shared__ float sAl[NREG], sAr[NREG], sInv[NREG];

  // phase A: zero P, load al/ar, load bucket slice
  for (int i = t; i < 128 * LDP / 2; i += 256) ((unsigned*)sP)[i] = 0u;
  if (t < NREG) {
    sAl[t] = b2f(Ht[(size_t)(D + h) * NN + gbase + t]);
    sAr[t] = b2f(Ht[(size_t)(D + 8 + h) * NN + gbase + t]);
  }
  for (int i = t; i < NREG * MAXDEG; i += 256) {
    int v = bucket[gbase * MAXDEG + i] - gbase;
    sBkt[i] = (unsigned short)(((unsigned)v < NREG) ? v : 0);
  }
  __syncthreads();

  // phase B: per-dst softmax -> unnormalized P row + 1/den
  if (t < NREG) {
    int d = t;
    int deg = cnt[gbase + d]; deg = deg > MAXDEG ? MAXDEG : deg;
    float ard = sAr[d];
    float lgs = sAl[d] + ard; lgs = lgs > 0.f ? lgs : 0.2f * lgs;   // self loop
    float m = lgs;
    for (int e = 0; e < deg; ++e) {
      float lg = sAl[sBkt[d * MAXDEG + e]] + ard; lg = lg > 0.f ? lg : 0.2f * lg;
      m = fmaxf(m, lg);
    }
    float den = expf(lgs - m);
    { bf16* p = (bf16*)&sP[d * LDP + d]; *p = f2b(b2f(*p) + expf(lgs - m)); }
    for (int e = 0; e < deg; ++e) {
      int s = sBkt[d * MAXDEG + e];
      float lg = sAl[s] + ard; lg = lg > 0.f ? lg : 0.2f * lg;
      float x = expf(lg - m); den += x;
      bf16* p = (bf16*)&sP[d * LDP + s]; *p = f2b(b2f(*p) + x);   // duplicates accumulate
    }
    sInv[d] = 1.f / den;
  }
  __syncthreads();

  // phase C: chunks of <=128 output cols; MFMA P[128x128] @ Hchunk^T
  constexpr int MT = (C >= 128) ? 4 : 2;
  constexpr int NCH = (C >= 128) ? C / 128 : 1;
  constexpr int CROWS = (C >= 128) ? 128 : 64;
  int m0w = (C >= 128) ? (wave >> 1) * 64 : wave * 32;
  int n0w = (C >= 128) ? (wave & 1) * 64 : 0;
  for (int ch = 0; ch < NCH; ++ch) {
    for (int job = t; job < CROWS * 32; job += 256) {
      int r = job >> 5, sl = job & 31;
      if (sl < 29)
        *(uint2*)&sHT[r * LDP + sl * 4] = *(const uint2*)&Ht[(size_t)(h * C + ch * 128 + r) * NN + gbase + sl * 4];
      else
        *(uint2*)&sHT[r * LDP + sl * 4] = make_uint2(0u, 0u);
    }
    __syncthreads();
    f32x4 acc[MT][4];
#pragma unroll
    for (int mt = 0; mt < MT; ++mt)
#pragma unroll
      for (int ct = 0; ct < 4; ++ct)
#pragma unroll
        for (int r = 0; r < 4; ++r) acc[mt][ct][r] = 0.f;
#pragma unroll
    for (int k4 = 0; k4 < 4; ++k4) {
      short8 af[MT], bfr[4];
#pragma unroll
      for (int mt = 0; mt < MT; ++mt)
        af[mt] = *(const short8*)&sP[(m0w + mt * 16 + ml) * LDP + k4 * 32 + quad * 8];
#pragma unroll
      for (int ct = 0; ct < 4; ++ct)
        bfr[ct] = *(const short8*)&sHT[(n0w + ct * 16 + ml) * LDP + k4 * 32 + quad * 8];
#pragma unroll
      for (int mt = 0; mt < MT; ++mt)
#pragma unroll
        for (int ct = 0; ct < 4; ++ct)
          acc[mt][ct] = __builtin_amdgcn_mfma_f32_16x16x32_bf16(af[mt], bfr[ct], acc[mt][ct], 0, 0, 0);
    }
#pragma unroll
    for (int mt = 0; mt < MT; ++mt)
#pragma unroll
      for (int ct = 0; ct < 4; ++ct) {
        int row0 = m0w + mt * 16 + quad * 4;
#pragma unroll
        for (int r = 0; r < 4; ++r) {
          int row = row0 + r;
          if (row < NREG)
            Xo[(size_t)(gbase + row) * D + h * C + ch * 128 + n0w + ct * 16 + ml] =
                f2b(acc[mt][ct][r] * sInv[row]);
        }
      }
    __syncthreads();
  }
}

// ---------------- epilogue: bias + ELU + LayerNorm (head-mean for last layer) ----------------
template<int C, int CONCAT>
__global__ __launch_bounds__(256) void k_post(const bf16* __restrict__ Hb, const void* __restrict__ bias,
                                              const void* __restrict__ ls, const void* __restrict__ lb,
                                              bf16* __restrict__ Xout, const int* __restrict__ flags) {
  constexpr int D = 8 * C;
  constexpr int V = D / 256;
  int wF = flags[1];
  int d = blockIdx.x, t = threadIdx.x;
  int lane = t & 63, wave = t >> 6;
  __shared__ float vals[CONCAT ? 8 : 512];
  __shared__ float r1[4], r2[4];
  __shared__ float sMu, sRs;
  int base = t * V;
  bf16 hv[V];
  if constexpr (V == 8) *(uint4*)hv = *(const uint4*)&Hb[(size_t)d * D + base];
  else if constexpr (V == 4) *(uint2*)hv = *(const uint2*)&Hb[(size_t)d * D + base];
  else *(unsigned*)hv = *(const unsigned*)&Hb[(size_t)d * D + base];

  if constexpr (CONCAT) {
    float acc[V];
    float s1 = 0.f, s2 = 0.f;
#pragma unroll
    for (int i = 0; i < V; ++i) {
      float v = b2f(hv[i]) + ldsel(bias, base + i, wF);
      v = v > 0.f ? v : expf(v) - 1.f;        // ELU
      acc[i] = v; s1 += v; s2 += v * v;
    }
#pragma unroll
    for (int off = 32; off; off >>= 1) { s1 += __shfl_down(s1, off); s2 += __shfl_down(s2, off); }
    if (lane == 0) { r1[wave] = s1; r2[wave] = s2; }
    __syncthreads();
    if (t == 0) {
      float S1 = r1[0] + r1[1] + r1[2] + r1[3];
      float S2 = r2[0] + r2[1] + r2[2] + r2[3];
      float mu = S1 / D;
      sMu = mu; sRs = rsqrtf(S2 / D - mu * mu + 1e-5f);
    }
    __syncthreads();
    bf16 ov[V];
#pragma unroll
    for (int i = 0; i < V; ++i)
      ov[i] = f2b((acc[i] - sMu) * sRs * ldsel(ls, base + i, wF) + ldsel(lb, base + i, wF));
    if constexpr (V == 8) *(uint4*)&Xout[(size_t)d * D + base] = *(uint4*)ov;
    else *(uint2*)&Xout[(size_t)d * D + base] = *(uint2*)ov;
  } else {
#pragma unroll
    for (int i = 0; i < V; ++i) vals[base + i] = b2f(hv[i]);
    __syncthreads();
    if (t < 64) {   // mean over 8 heads -> 64 dims, ELU, LN over 64
      float v = 0.f;
#pragma unroll
      for (int hh = 0; hh < 8; ++hh) v += vals[hh * 64 + t];
      v = v * 0.125f + ldsel(bias, t, wF);
      v = v > 0.f ? v : expf(v) - 1.f;
      float s1 = v, s2 = v * v;
#pragma unroll
      for (int off = 32; off; off >>= 1) { s1 += __shfl_xor(s1, off); s2 += __shfl_xor(s2, off); }
      float mu = s1 * (1.f / 64.f);
      float var = s2 * (1.f / 64.f) - mu * mu;
      float rs = rsqrtf(var + 1e-5f);
      Xout[(size_t)d * 64 + t] = f2b((v - mu) * rs * ldsel(ls, t, wF) + ldsel(lb, t, wF));
    }
  }
}

// ---------------- projection (64->256) + LN + GELU(erf) + q ----------------
__global__ __launch_bounds__(256) void k_proj(const bf16* __restrict__ X3, const void* __restrict__ wp,
                                              const void* __restrict__ bp, const void* __restrict__ lsp,
                                              const void* __restrict__ lbp, const void* __restrict__ wq,
                                              const void* __restrict__ bq,
                                              float* __restrict__ q, void* __restrict__ dout,
                                              const int* __restrict__ flags) {
  int wF = flags[1], xF = flags[0];
  int n = blockIdx.x, t = threadIdx.x;
  int lane = t & 63, wave = t >> 6;
  __shared__ float xs[64];
  __shared__ float r1[4], r2[4];
  __shared__ float sMu, sRs;
  if (t < 64) xs[t] = b2f(X3[n * 64 + t]);
  __syncthreads();
  float y = ldsel(bp, t, wF);
#pragma unroll 8
  for (int k = 0; k < 64; ++k) y = fmaf(xs[k], ldsel(wp, k * 256 + t, wF), y);
  float s1 = y, s2 = y * y;
#pragma unroll
  for (int off = 32; off; off >>= 1) { s1 += __shfl_down(s1, off); s2 += __shfl_down(s2, off); }
  if (lane == 0) { r1[wave] = s1; r2[wave] = s2; }
  __syncthreads();
  if (t == 0) {
    float S1 = r1[0] + r1[1] + r1[2] + r1[3];
    float S2 = r2[0] + r2[1] + r2[2] + r2[3];
    float mu = S1 / 256.f;
    sMu = mu; sRs = rsqrtf(S2 / 256.f - mu * mu + 1e-5f);
  }
  __syncthreads();
  float v = (y - sMu) * sRs * ldsel(lsp, t, wF) + ldsel(lbp, t, wF);
  float g = 0.5f * v * (1.f + erff(v * 0.70710678118654752f));   // exact GELU
  stsel(dout, (size_t)NG * 256 + (size_t)n * 256 + t, g, xF);    // node_out
  float qv = g * ldsel(wq, t, wF);
#pragma unroll
  for (int off = 32; off; off >>= 1) qv += __shfl_down(qv, off);
  if (lane == 0) r1[wave] = qv;
  __syncthreads();
  if (t == 0) q[n] = r1[0] + r1[1] + r1[2] + r1[3] + ldsel(bq, 0, wF);
}

// ---------------- attention pooling per graph ----------------
__global__ __launch_bounds__(256) void k_pool(void* __restrict__ dout, const float* __restrict__ q,
                                              const int* __restrict__ flags) {
  int xF = flags[0];
  int b = blockIdx.x, t = threadIdx.x;
  __shared__ float es[NREG];
  __shared__ float sDen;
  if (t < NREG) es[t] = q[b * NREG + t];
  __syncthreads();
  if (t == 0) {
    float m = -1e30f;
    for (int i = 0; i < NREG; ++i) m = fmaxf(m, es[i]);
    float den = 0.f;
    for (int i = 0; i < NREG; ++i) { float e = expf(es[i] - m); es[i] = e; den += e; }
    sDen = den;
  }
  __syncthreads();
  float acc = 0.f;
  for (int i = 0; i < NREG; ++i)
    acc = fmaf(es[i], ldsel(dout, (size_t)NG * 256 + (size_t)(b * NREG + i) * 256 + t, xF), acc);
  stsel(dout, (size_t)b * 256 + t, acc / sDen, xF);
}

// ---------------- launcher ----------------
extern "C" void kernel_launch(void* const* d_in, const int* in_sizes, int n_in,
                              void* d_out, int out_size, void* d_ws, size_t ws_size,
                              hipStream_t stream) {
  const void* nf  = d_in[0];
  const int* src  = (const int*)d_in[1];
  const int* dst  = (const int*)d_in[2];
  const void *w0 = d_in[4],  *b0 = d_in[5],  *as0 = d_in[6], *ad0 = d_in[7],  *ls0 = d_in[8],  *lb0 = d_in[9];
  const void *w1 = d_in[10], *b1 = d_in[11], *as1 = d_in[12], *ad1 = d_in[13], *ls1 = d_in[14], *lb1 = d_in[15];
  const void *w2 = d_in[16], *b2 = d_in[17], *as2 = d_in[18], *ad2 = d_in[19], *ls2 = d_in[20], *lb2 = d_in[21];
  const void *wp = d_in[22], *bp = d_in[23], *lsp = d_in[24], *lbp = d_in[25], *wq = d_in[26], *bq = d_in[27];

  // workspace layout — TOTAL ~31.9 MB
  int* flags  = (int*)d_ws;                       // 4 ints
  int* cnt    = flags + 4;                        // NN
  int* bucket = cnt + NN;                         // NN*MAXDEG(32)
  float* q    = (float*)(bucket + NN * MAXDEG);   // NN f32
  bf16* X     = (bf16*)(q + NN);                  // NN*2048 bf16 (16B-aligned)
  bf16* Ht    = X + (size_t)NN * 2048;            // 2176*NN bf16 (feat-major)

  bf16* X0  = X;                                  // NN*256 input copy (dead after gemm0)
  bf16* wt0 = X + (1 << 20);                      // 2176 x 256  (in X region, dead after gemm0)
  bf16* wt1 = Ht + (size_t)4500 * 1024;           // 1152 x 2048 (above gemm1's 1152*NN output)
  bf16* wt2 = Ht + (size_t)4500 * 1024;           // 640 x 1024  (above gemm2's 640*NN output)
  bf16* X2  = X + (size_t)4 * 1024 * 1024;        // NN*64 final LN output (clear of NN*512 region)

  k_detect<<<1, 256, 0, stream>>>(nf, w0, flags);
  k_zero<<<(NN + 255) / 256, 256, 0, stream>>>(cnt, NN);
  k_scatter<<<(NE + 255) / 256, 256, 0, stream>>>(src, dst, cnt, bucket, NE);
  k_tobf16<<<(NN * 256 + 255) / 256, 256, 0, stream>>>(nf, X0, NN * 256, flags, 0);

  // layer 0: 256 -> 2048 (+16 alr rows, N'=2176)
  k_transpose<<<dim3(256 / 32, 2048 / 32), 256, 0, stream>>>(w0, wt0, 256, 2048, flags);
  k_prew2<<<dim3(256 / 256, 8), 256, 0, stream>>>(as0, ad0, wt0, 256, 2048, 256, flags);
  k_gemm_t<128, 128><<<dim3(2176 / 128, NN / 128), 256, 0, stream>>>(X0, wt0, Ht, NN, 256);
  k_gagg2<256><<<NG * 8, 256, 0, stream>>>(Ht, X, cnt, bucket);
  k_post<256, 1><<<NN, 256, 0, stream>>>(X, b0, ls0, lb0, X, flags);

  // layer 1: 2048 -> 1024 (+16, N'=1152)
  k_transpose<<<dim3(2048 / 32, 1024 / 32), 256, 0, stream>>>(w1, wt1, 2048, 1024, flags);
  k_prew2<<<dim3(2048 / 256, 8), 256, 0, stream>>>(as1, ad1, wt1, 2048, 1024, 128, flags);
  k_gemm_t<64, 128><<<dim3(1152 / 128, NN / 64), 256, 0, stream>>>(X, wt1, Ht, NN, 2048);
  k_gagg2<128><<<NG * 8, 256, 0, stream>>>(Ht, X, cnt, bucket);
  k_post<128, 1><<<NN, 256, 0, stream>>>(X, b1, ls1, lb1, X, flags);

  // layer 2: 1024 -> 512 (+16, N'=640)
  k_transpose<<<dim3(1024 / 32, 512 / 32), 256, 0, stream>>>(w2, wt2, 1024, 512, flags);
  k_prew2<<<dim3(1024 / 256, 8), 256, 0, stream>>>(as2, ad2, wt2, 1024, 512, 64, flags);
  k_gemm_t<64, 128><<<dim3(640 / 128, NN / 64), 256, 0, stream>>>(X, wt2, Ht, NN, 1024);
  k_gagg2<64><<<NG * 8, 256, 0, stream>>>(Ht, X, cnt, bucket);
  k_post<64, 0><<<NN, 256, 0, stream>>>(X, b2, ls2, lb2, X2, flags);

  // projection + GELU + q, then pooling
  k_proj<<<NN, 256, 0, stream>>>(X2, wp, bp, lsp, lbp, wq, bq, q, d_out, flags);
  k_pool<<<NG, 256, 0, stream>>>(d_out, q, flags);
}

// Round 9
// 549.204 us; speedup vs baseline: 1.8772x; 1.2244x over previous
//
#include <hip/hip_runtime.h>
#include <hip/hip_bf16.h>
#include <math.h>

typedef __hip_bfloat16 bf16;
typedef short short8 __attribute__((ext_vector_type(8)));
typedef float f32x4 __attribute__((ext_vector_type(4)));

__device__ __forceinline__ float b2f(const bf16 v) { return __bfloat162float(v); }
__device__ __forceinline__ bf16 f2b(const float v) { return __float2bfloat16(v); }

__device__ __forceinline__ float ldsel(const void* p, size_t i, int f32) {
  return f32 ? ((const float*)p)[i] : b2f(((const bf16*)p)[i]);
}
__device__ __forceinline__ void stsel(void* p, size_t i, float v, int f32) {
  if (f32) ((float*)p)[i] = v; else ((bf16*)p)[i] = f2b(v);
}

#define NN 3712          // nodes
#define NE 37120         // edges (without self loops)
#define NG 32            // graphs
#define NREG 116         // nodes per graph
#define MAXDEG 32        // bucket capacity (in-degree ~ Poisson(10); P(>32) ~ 1e-9)

// ---------------- dtype detector ----------------
__global__ __launch_bounds__(256) void k_detect(const void* nf, const void* w0, int* flags) {
  __shared__ int bad[2];
  if (threadIdx.x < 2) bad[threadIdx.x] = 0;
  __syncthreads();
  const bf16* a = (const bf16*)nf;
  const bf16* b = (const bf16*)w0;
  int l0 = 0, l1 = 0;
  for (int i = threadIdx.x; i < 4096; i += 256) {
    float x = b2f(a[i]); if (!(fabsf(x) < 1e4f)) l0++;
    float y = b2f(b[i]); if (!(fabsf(y) < 1e4f)) l1++;
  }
  if (l0) atomicAdd(&bad[0], l0);
  if (l1) atomicAdd(&bad[1], l1);
  __syncthreads();
  if (threadIdx.x == 0) { flags[0] = bad[0] > 0; flags[1] = bad[1] > 0; }
}

// ---------------- utility kernels ----------------
__global__ __launch_bounds__(256) void k_zero(int* __restrict__ p, int n) {
  int i = blockIdx.x * 256 + threadIdx.x;
  if (i < n) p[i] = 0;
}

__global__ __launch_bounds__(256) void k_scatter(const int* __restrict__ src, const int* __restrict__ dst,
                                                 int* __restrict__ cnt, int* __restrict__ bucket, int E) {
  int e = blockIdx.x * 256 + threadIdx.x;
  if (e < E) {
    int d = dst[e], s = src[e];
    if ((unsigned)d < NN && (unsigned)s < NN) {
      int p = atomicAdd(&cnt[d], 1);
      if (p < MAXDEG) bucket[d * MAXDEG + p] = s;
    }
  }
}

__global__ __launch_bounds__(256) void k_tobf16(const void* __restrict__ in, bf16* __restrict__ out,
                                                int n, const int* __restrict__ flags, int fidx) {
  int f = flags[fidx];
  int i = blockIdx.x * 256 + threadIdx.x;
  if (i < n) out[i] = f2b(ldsel(in, i, f));
}

// transpose W[K][N] -> Wt[N][K], bf16 out. K,N multiples of 32.
__global__ __launch_bounds__(256) void k_transpose(const void* __restrict__ W, bf16* __restrict__ Wt,
                                                   int K, int N, const int* __restrict__ flags) {
  int f = flags[1];
  __shared__ float tile[32][33];
  int tx = threadIdx.x & 31, ty = threadIdx.x >> 5;
  int k0 = blockIdx.x * 32, n0 = blockIdx.y * 32;
#pragma unroll
  for (int i = 0; i < 4; ++i)
    tile[ty + i * 8][tx] = ldsel(W, (size_t)(k0 + ty + i * 8) * N + n0 + tx, f);
  __syncthreads();
#pragma unroll
  for (int i = 0; i < 4; ++i)
    Wt[(size_t)(n0 + ty + i * 8) * K + k0 + tx] = f2b(tile[tx][ty + i * 8]);
}

// fold attention vectors into extra wt rows (reads already-transposed wt, coalesced):
//   wt[N+j][k] = sum_c wt[j*C+c][k]*a_s[j][c];  wt[N+8+j][k] = ... a_d ...
__global__ __launch_bounds__(256) void k_prew2(const void* __restrict__ a_s, const void* __restrict__ a_d,
                                               bf16* __restrict__ wt, int K, int N, int C,
                                               const int* __restrict__ flags) {
  int wF = flags[1];
  int j = blockIdx.y;
  int k = blockIdx.x * 256 + threadIdx.x;
  float sS = 0.f, sD = 0.f;
  for (int c = 0; c < C; ++c) {
    float w = b2f(wt[(size_t)(j * C + c) * K + k]);
    sS = fmaf(w, ldsel(a_s, j * C + c, wF), sS);
    sD = fmaf(w, ldsel(a_d, j * C + c, wF), sD);
  }
  wt[(size_t)(N + j) * K + k] = f2b(sS);
  wt[(size_t)(N + 8 + j) * K + k] = f2b(sD);
}

// ---------------- MFMA bf16 NT GEMM, node-major store with row stride NS ----------------
// C[m][n] (stride NS) = sum_k A[m][k] * Bt[n][k].  128x128 tile, BK=32, reg prefetch.
__global__ __launch_bounds__(256) void k_gemm_mfma(const bf16* __restrict__ A, const bf16* __restrict__ Bt,
                                                   bf16* __restrict__ C_, int NS, int M, int K) {
  __shared__ short As[128 * 40];
  __shared__ short Bs[128 * 40];
  int tid = threadIdx.x, wave = tid >> 6, lane = tid & 63;
  int wr = wave >> 1, wc = wave & 1;
  int quad = lane >> 4, ml = lane & 15;
  int m0 = blockIdx.y * 128, n0 = blockIdx.x * 128;
  int r0 = tid >> 2, kg = (tid & 3) * 8;
  int r1 = r0 + 64;
  f32x4 acc[4][4];
#pragma unroll
  for (int rt = 0; rt < 4; ++rt)
#pragma unroll
    for (int ct = 0; ct < 4; ++ct)
#pragma unroll
      for (int r = 0; r < 4; ++r) acc[rt][ct][r] = 0.f;

  uint4 pa0 = *(const uint4*)&A[(size_t)(m0 + r0) * K + kg];
  uint4 pa1 = *(const uint4*)&A[(size_t)(m0 + r1) * K + kg];
  uint4 pb0 = *(const uint4*)&Bt[(size_t)(n0 + r0) * K + kg];
  uint4 pb1 = *(const uint4*)&Bt[(size_t)(n0 + r1) * K + kg];

  int nk = K >> 5;
  for (int ks = 0; ks < nk; ++ks) {
    *(uint4*)&As[r0 * 40 + kg] = pa0;
    *(uint4*)&As[r1 * 40 + kg] = pa1;
    *(uint4*)&Bs[r0 * 40 + kg] = pb0;
    *(uint4*)&Bs[r1 * 40 + kg] = pb1;
    __syncthreads();
    if (ks + 1 < nk) {
      int k0 = (ks + 1) << 5;
      pa0 = *(const uint4*)&A[(size_t)(m0 + r0) * K + k0 + kg];
      pa1 = *(const uint4*)&A[(size_t)(m0 + r1) * K + k0 + kg];
      pb0 = *(const uint4*)&Bt[(size_t)(n0 + r0) * K + k0 + kg];
      pb1 = *(const uint4*)&Bt[(size_t)(n0 + r1) * K + k0 + kg];
    }
    short8 af[4], bfr[4];
#pragma unroll
    for (int rt = 0; rt < 4; ++rt)
      af[rt] = *(const short8*)&As[(wr * 64 + rt * 16 + ml) * 40 + quad * 8];
#pragma unroll
    for (int ct = 0; ct < 4; ++ct)
      bfr[ct] = *(const short8*)&Bs[(wc * 64 + ct * 16 + ml) * 40 + quad * 8];
#pragma unroll
    for (int rt = 0; rt < 4; ++rt)
#pragma unroll
      for (int ct = 0; ct < 4; ++ct)
        acc[rt][ct] = __builtin_amdgcn_mfma_f32_16x16x32_bf16(af[rt], bfr[ct], acc[rt][ct], 0, 0, 0);
    __syncthreads();
  }
#pragma unroll
  for (int rt = 0; rt < 4; ++rt)
#pragma unroll
    for (int ct = 0; ct < 4; ++ct)
#pragma unroll
      for (int r = 0; r < 4; ++r) {
        int grow = m0 + wr * 64 + rt * 16 + quad * 4 + r;
        int gcol = n0 + wc * 64 + ct * 16 + ml;
        C_[(size_t)grow * NS + gcol] = f2b(acc[rt][ct][r]);
      }
}

// ---------------- fused GAT attention+aggregation as P@H MFMA (node-major H) ----------------
// One block per (g,h). Hn node-major rows of length NS; cols D+h / D+8+h hold al/ar.
// Dense softmax-adjacency P (unnormalized bf16) in LDS; B-operand H^T built by LDS transpose.
template<int C>
__global__ __launch_bounds__(256) void k_gagg3(const bf16* __restrict__ Hn, int NS, bf16* __restrict__ Xo,
                                               const int* __restrict__ cnt, const int* __restrict__ bucket) {
  constexpr int D = 8 * C;
  constexpr int LDP = 136;              // shorts; 272 B rows
  int g = blockIdx.x >> 3, h = blockIdx.x & 7;
  int t = threadIdx.x, lane = t & 63, wave = t >> 6;
  int quad = lane >> 4, ml = lane & 15;
  int gbase = g * NREG;
  __shared__ short sP[128 * LDP];
  __shared__ short sHT[128 * LDP];
  __shared__ unsigned short sBkt[NREG * MAXDEG];
  __shared__ float sAl[NREG], sAr[NREG], sInv[NREG];

  // phase A: zero sP+sHT, load al/ar (2 scalar loads per dst), load bucket slice
  for (int i = t; i < 128 * LDP / 2; i += 256) { ((unsigned*)sP)[i] = 0u; ((unsigned*)sHT)[i] = 0u; }
  if (t < NREG) {
    sAl[t] = b2f(Hn[(size_t)(gbase + t) * NS + D + h]);
    sAr[t] = b2f(Hn[(size_t)(gbase + t) * NS + D + 8 + h]);
  }
  for (int i = t; i < NREG * MAXDEG; i += 256) {
    int v = bucket[gbase * MAXDEG + i] - gbase;
    sBkt[i] = (unsigned short)(((unsigned)v < NREG) ? v : 0);
  }
  __syncthreads();

  // phase B: per-dst softmax -> unnormalized P row + 1/den
  if (t < NREG) {
    int d = t;
    int deg = cnt[gbase + d]; deg = deg > MAXDEG ? MAXDEG : deg;
    float ard = sAr[d];
    float lgs = sAl[d] + ard; lgs = lgs > 0.f ? lgs : 0.2f * lgs;   // self loop
    float m = lgs;
    for (int e = 0; e < deg; ++e) {
      float lg = sAl[sBkt[d * MAXDEG + e]] + ard; lg = lg > 0.f ? lg : 0.2f * lg;
      m = fmaxf(m, lg);
    }
    float den = expf(lgs - m);
    { bf16* p = (bf16*)&sP[d * LDP + d]; *p = f2b(b2f(*p) + expf(lgs - m)); }
    for (int e = 0; e < deg; ++e) {
      int s = sBkt[d * MAXDEG + e];
      float lg = sAl[s] + ard; lg = lg > 0.f ? lg : 0.2f * lg;
      float x = expf(lg - m); den += x;
      bf16* p = (bf16*)&sP[d * LDP + s]; *p = f2b(b2f(*p) + x);   // duplicates accumulate
    }
    sInv[d] = 1.f / den;
  }
  __syncthreads();

  // phase C: chunks of <=128 output cols; MFMA P[128x128] @ Hchunk^T
  constexpr int MT = (C >= 128) ? 4 : 2;
  constexpr int NCH = (C >= 128) ? C / 128 : 1;
  constexpr int CROWS = (C >= 128) ? 128 : 64;
  int m0w = (C >= 128) ? (wave >> 1) * 64 : wave * 32;
  int n0w = (C >= 128) ? (wave & 1) * 64 : 0;
  for (int ch = 0; ch < NCH; ++ch) {
    // load H chunk node-major (coalesced 16B/lane), transpose into sHT[col][node]
    for (int job = t; job < NREG * (CROWS / 8); job += 256) {
      int node = job / (CROWS / 8), cc = job % (CROWS / 8);
      bf16 hv[8];
      *(uint4*)hv = *(const uint4*)&Hn[(size_t)(gbase + node) * NS + h * C + ch * 128 + cc * 8];
#pragma unroll
      for (int i = 0; i < 8; ++i) sHT[(cc * 8 + i) * LDP + node] = *(short*)&hv[i];
    }
    __syncthreads();
    f32x4 acc[MT][4];
#pragma unroll
    for (int mt = 0; mt < MT; ++mt)
#pragma unroll
      for (int ct = 0; ct < 4; ++ct)
#pragma unroll
        for (int r = 0; r < 4; ++r) acc[mt][ct][r] = 0.f;
#pragma unroll
    for (int k4 = 0; k4 < 4; ++k4) {
      short8 af[MT], bfr[4];
#pragma unroll
      for (int mt = 0; mt < MT; ++mt)
        af[mt] = *(const short8*)&sP[(m0w + mt * 16 + ml) * LDP + k4 * 32 + quad * 8];
#pragma unroll
      for (int ct = 0; ct < 4; ++ct)
        bfr[ct] = *(const short8*)&sHT[(n0w + ct * 16 + ml) * LDP + k4 * 32 + quad * 8];
#pragma unroll
      for (int mt = 0; mt < MT; ++mt)
#pragma unroll
        for (int ct = 0; ct < 4; ++ct)
          acc[mt][ct] = __builtin_amdgcn_mfma_f32_16x16x32_bf16(af[mt], bfr[ct], acc[mt][ct], 0, 0, 0);
    }
#pragma unroll
    for (int mt = 0; mt < MT; ++mt)
#pragma unroll
      for (int ct = 0; ct < 4; ++ct) {
        int row0 = m0w + mt * 16 + quad * 4;
#pragma unroll
        for (int r = 0; r < 4; ++r) {
          int row = row0 + r;
          if (row < NREG)
            Xo[(size_t)(gbase + row) * D + h * C + ch * 128 + n0w + ct * 16 + ml] =
                f2b(acc[mt][ct][r] * sInv[row]);
        }
      }
    __syncthreads();
  }
}

// ---------------- epilogue: bias + ELU + LayerNorm (head-mean for last layer) ----------------
template<int C, int CONCAT>
__global__ __launch_bounds__(256) void k_post(const bf16* __restrict__ Hb, const void* __restrict__ bias,
                                              const void* __restrict__ ls, const void* __restrict__ lb,
                                              bf16* __restrict__ Xout, const int* __restrict__ flags) {
  constexpr int D = 8 * C;
  constexpr int V = D / 256;
  int wF = flags[1];
  int d = blockIdx.x, t = threadIdx.x;
  int lane = t & 63, wave = t >> 6;
  __shared__ float vals[CONCAT ? 8 : 512];
  __shared__ float r1[4], r2[4];
  __shared__ float sMu, sRs;
  int base = t * V;
  bf16 hv[V];
  if constexpr (V == 8) *(uint4*)hv = *(const uint4*)&Hb[(size_t)d * D + base];
  else if constexpr (V == 4) *(uint2*)hv = *(const uint2*)&Hb[(size_t)d * D + base];
  else *(unsigned*)hv = *(const unsigned*)&Hb[(size_t)d * D + base];

  if constexpr (CONCAT) {
    float acc[V];
    float s1 = 0.f, s2 = 0.f;
#pragma unroll
    for (int i = 0; i < V; ++i) {
      float v = b2f(hv[i]) + ldsel(bias, base + i, wF);
      v = v > 0.f ? v : expf(v) - 1.f;        // ELU
      acc[i] = v; s1 += v; s2 += v * v;
    }
#pragma unroll
    for (int off = 32; off; off >>= 1) { s1 += __shfl_down(s1, off); s2 += __shfl_down(s2, off); }
    if (lane == 0) { r1[wave] = s1; r2[wave] = s2; }
    __syncthreads();
    if (t == 0) {
      float S1 = r1[0] + r1[1] + r1[2] + r1[3];
      float S2 = r2[0] + r2[1] + r2[2] + r2[3];
      float mu = S1 / D;
      sMu = mu; sRs = rsqrtf(S2 / D - mu * mu + 1e-5f);
    }
    __syncthreads();
    bf16 ov[V];
#pragma unroll
    for (int i = 0; i < V; ++i)
      ov[i] = f2b((acc[i] - sMu) * sRs * ldsel(ls, base + i, wF) + ldsel(lb, base + i, wF));
    if constexpr (V == 8) *(uint4*)&Xout[(size_t)d * D + base] = *(uint4*)ov;
    else *(uint2*)&Xout[(size_t)d * D + base] = *(uint2*)ov;
  } else {
#pragma unroll
    for (int i = 0; i < V; ++i) vals[base + i] = b2f(hv[i]);
    __syncthreads();
    if (t < 64) {   // mean over 8 heads -> 64 dims, ELU, LN over 64
      float v = 0.f;
#pragma unroll
      for (int hh = 0; hh < 8; ++hh) v += vals[hh * 64 + t];
      v = v * 0.125f + ldsel(bias, t, wF);
      v = v > 0.f ? v : expf(v) - 1.f;
      float s1 = v, s2 = v * v;
#pragma unroll
      for (int off = 32; off; off >>= 1) { s1 += __shfl_xor(s1, off); s2 += __shfl_xor(s2, off); }
      float mu = s1 * (1.f / 64.f);
      float var = s2 * (1.f / 64.f) - mu * mu;
      float rs = rsqrtf(var + 1e-5f);
      Xout[(size_t)d * 64 + t] = f2b((v - mu) * rs * ldsel(ls, t, wF) + ldsel(lb, t, wF));
    }
  }
}

// ---------------- projection (64->256) + LN + GELU(erf) + q ----------------
__global__ __launch_bounds__(256) void k_proj(const bf16* __restrict__ X3, const void* __restrict__ wp,
                                              const void* __restrict__ bp, const void* __restrict__ lsp,
                                              const void* __restrict__ lbp, const void* __restrict__ wq,
                                              const void* __restrict__ bq,
                                              float* __restrict__ q, void* __restrict__ dout,
                                              const int* __restrict__ flags) {
  int wF = flags[1], xF = flags[0];
  int n = blockIdx.x, t = threadIdx.x;
  int lane = t & 63, wave = t >> 6;
  __shared__ float xs[64];
  __shared__ float r1[4], r2[4];
  __shared__ float sMu, sRs;
  if (t < 64) xs[t] = b2f(X3[n * 64 + t]);
  __syncthreads();
  float y = ldsel(bp, t, wF);
#pragma unroll 8
  for (int k = 0; k < 64; ++k) y = fmaf(xs[k], ldsel(wp, k * 256 + t, wF), y);
  float s1 = y, s2 = y * y;
#pragma unroll
  for (int off = 32; off; off >>= 1) { s1 += __shfl_down(s1, off); s2 += __shfl_down(s2, off); }
  if (lane == 0) { r1[wave] = s1; r2[wave] = s2; }
  __syncthreads();
  if (t == 0) {
    float S1 = r1[0] + r1[1] + r1[2] + r1[3];
    float S2 = r2[0] + r2[1] + r2[2] + r2[3];
    float mu = S1 / 256.f;
    sMu = mu; sRs = rsqrtf(S2 / 256.f - mu * mu + 1e-5f);
  }
  __syncthreads();
  float v = (y - sMu) * sRs * ldsel(lsp, t, wF) + ldsel(lbp, t, wF);
  float g = 0.5f * v * (1.f + erff(v * 0.70710678118654752f));   // exact GELU
  stsel(dout, (size_t)NG * 256 + (size_t)n * 256 + t, g, xF);    // node_out
  float qv = g * ldsel(wq, t, wF);
#pragma unroll
  for (int off = 32; off; off >>= 1) qv += __shfl_down(qv, off);
  if (lane == 0) r1[wave] = qv;
  __syncthreads();
  if (t == 0) q[n] = r1[0] + r1[1] + r1[2] + r1[3] + ldsel(bq, 0, wF);
}

// ---------------- attention pooling per graph ----------------
__global__ __launch_bounds__(256) void k_pool(void* __restrict__ dout, const float* __restrict__ q,
                                              const int* __restrict__ flags) {
  int xF = flags[0];
  int b = blockIdx.x, t = threadIdx.x;
  __shared__ float es[NREG];
  __shared__ float sDen;
  if (t < NREG) es[t] = q[b * NREG + t];
  __syncthreads();
  if (t == 0) {
    float m = -1e30f;
    for (int i = 0; i < NREG; ++i) m = fmaxf(m, es[i]);
    float den = 0.f;
    for (int i = 0; i < NREG; ++i) { float e = expf(es[i] - m); es[i] = e; den += e; }
    sDen = den;
  }
  __syncthreads();
  float acc = 0.f;
  for (int i = 0; i < NREG; ++i)
    acc = fmaf(es[i], ldsel(dout, (size_t)NG * 256 + (size_t)(b * NREG + i) * 256 + t, xF), acc);
  stsel(dout, (size_t)b * 256 + t, acc / sDen, xF);
}

// ---------------- launcher ----------------
extern "C" void kernel_launch(void* const* d_in, const int* in_sizes, int n_in,
                              void* d_out, int out_size, void* d_ws, size_t ws_size,
                              hipStream_t stream) {
  const void* nf  = d_in[0];
  const int* src  = (const int*)d_in[1];
  const int* dst  = (const int*)d_in[2];
  const void *w0 = d_in[4],  *b0 = d_in[5],  *as0 = d_in[6], *ad0 = d_in[7],  *ls0 = d_in[8],  *lb0 = d_in[9];
  const void *w1 = d_in[10], *b1 = d_in[11], *as1 = d_in[12], *ad1 = d_in[13], *ls1 = d_in[14], *lb1 = d_in[15];
  const void *w2 = d_in[16], *b2 = d_in[17], *as2 = d_in[18], *ad2 = d_in[19], *ls2 = d_in[20], *lb2 = d_in[21];
  const void *wp = d_in[22], *bp = d_in[23], *lsp = d_in[24], *lbp = d_in[25], *wq = d_in[26], *bq = d_in[27];

  // workspace layout — TOTAL ~31.9 MB (known-safe)
  int* flags  = (int*)d_ws;                       // 4 ints
  int* cnt    = flags + 4;                        // NN
  int* bucket = cnt + NN;                         // NN*MAXDEG(32)
  float* q    = (float*)(bucket + NN * MAXDEG);   // NN f32
  bf16* X     = (bf16*)(q + NN);                  // NN*2048 bf16 (16B-aligned)
  bf16* Hn    = X + (size_t)NN * 2048;            // NN*2176 bf16 (node-major, stride per layer)

  bf16* X0  = X;                                  // NN*256 input copy (dead after gemm0)
  bf16* wt0 = X + (1 << 21);                      // 2176 x 256  (within X region, dead after gemm0)
  bf16* wt1 = Hn + (size_t)NN * 1152;             // 1152 x 2048 (above gemm1's NN*1152 output)
  bf16* wt2 = Hn + (size_t)NN * 640;              // 640 x 1024  (above gemm2's NN*640 output)
  bf16* X2  = X + (size_t)4 * 1024 * 1024;        // NN*64 final LN output

  k_detect<<<1, 256, 0, stream>>>(nf, w0, flags);
  k_zero<<<(NN + 255) / 256, 256, 0, stream>>>(cnt, NN);
  k_scatter<<<(NE + 255) / 256, 256, 0, stream>>>(src, dst, cnt, bucket, NE);
  k_tobf16<<<(NN * 256 + 255) / 256, 256, 0, stream>>>(nf, X0, NN * 256, flags, 0);

  // layer 0: 256 -> 2048 (+16 al/ar cols, N2=2176), NS=2176
  k_transpose<<<dim3(256 / 32, 2048 / 32), 256, 0, stream>>>(w0, wt0, 256, 2048, flags);
  k_zero<<<(112 * 256 / 2 + 255) / 256, 256, 0, stream>>>((int*)(wt0 + (size_t)2064 * 256), 112 * 256 / 2);
  k_prew2<<<dim3(1, 8), 256, 0, stream>>>(as0, ad0, wt0, 256, 2048, 256, flags);
  k_gemm_mfma<<<dim3(2176 / 128, NN / 128), 256, 0, stream>>>(X0, wt0, Hn, 2176, NN, 256);
  k_gagg3<256><<<NG * 8, 256, 0, stream>>>(Hn, 2176, X, cnt, bucket);
  k_post<256, 1><<<NN, 256, 0, stream>>>(X, b0, ls0, lb0, X, flags);

  // layer 1: 2048 -> 1024 (+16, N2=1152), NS=1152
  k_transpose<<<dim3(2048 / 32, 1024 / 32), 256, 0, stream>>>(w1, wt1, 2048, 1024, flags);
  k_zero<<<(112 * 2048 / 2 + 255) / 256, 256, 0, stream>>>((int*)(wt1 + (size_t)1040 * 2048), 112 * 2048 / 2);
  k_prew2<<<dim3(2048 / 256, 8), 256, 0, stream>>>(as1, ad1, wt1, 2048, 1024, 128, flags);
  k_gemm_mfma<<<dim3(1152 / 128, NN / 128), 256, 0, stream>>>(X, wt1, Hn, 1152, NN, 2048);
  k_gagg3<128><<<NG * 8, 256, 0, stream>>>(Hn, 1152, X, cnt, bucket);
  k_post<128, 1><<<NN, 256, 0, stream>>>(X, b1, ls1, lb1, X, flags);

  // layer 2: 1024 -> 512 (+16, N2=640), NS=640
  k_transpose<<<dim3(1024 / 32, 512 / 32), 256, 0, stream>>>(w2, wt2, 1024, 512, flags);
  k_zero<<<(112 * 1024 / 2 + 255) / 256, 256, 0, stream>>>((int*)(wt2 + (size_t)528 * 1024), 112 * 1024 / 2);
  k_prew2<<<dim3(1024 / 256, 8), 256, 0, stream>>>(as2, ad2, wt2, 1024, 512, 64, flags);
  k_gemm_mfma<<<dim3(640 / 128, NN / 128), 256, 0, stream>>>(X, wt2, Hn, 640, NN, 1024);
  k_gagg3<64><<<NG * 8, 256, 0, stream>>>(Hn, 640, X, cnt, bucket);
  k_post<64, 0><<<NN, 256, 0, stream>>>(X, b2, ls2, lb2, X2, flags);

  // projection + GELU + q, then pooling
  k_proj<<<NN, 256, 0, stream>>>(X2, wp, bp, lsp, lbp, wq, bq, q, d_out, flags);
  k_pool<<<NG, 256, 0, stream>>>(d_out, q, flags);
}